// Round 8
// baseline (376.472 us; speedup 1.0000x reference)
//
#include <hip/hip_runtime.h>

// GraphSAGE 3-layer, N=50000, E=800000, D=128, D_OUT=64.
// R8: fused gather+MFMA layer kernel. Block = 64 nodes (4 waves, wave = 16
// nodes): phase 1 gathers agg rows into LDS (bf16, stride 136), phase 2 runs
// the 16x16x32 bf16 MFMA K-loop (A: global x-half + LDS agg-half; W hi+lo
// staged per-32-K chunk, stride 40). Saves the 25.6MB/layer agg round trip.

#define D 128
#define K2 256

typedef __attribute__((ext_vector_type(8))) short short8;
typedef __attribute__((ext_vector_type(4))) float floatx4;

__device__ inline unsigned short rne_bf16(float f) {
    unsigned int u = __float_as_uint(f);
    u += 0x7fffu + ((u >> 16) & 1u);
    return (unsigned short)(u >> 16);
}

// ---------- casts ----------
__global__ void cast_x_kernel(const float* __restrict__ in, unsigned short* __restrict__ out, int n4) {
    int i = blockIdx.x * blockDim.x + threadIdx.x;
    if (i >= n4) return;
    float4 v = reinterpret_cast<const float4*>(in)[i];
    ushort4 o;
    o.x = rne_bf16(v.x); o.y = rne_bf16(v.y); o.z = rne_bf16(v.z); o.w = rne_bf16(v.w);
    reinterpret_cast<ushort4*>(out)[i] = o;
}

__global__ void cast_w_kernel(const float* __restrict__ w, unsigned short* __restrict__ hi,
                              unsigned short* __restrict__ lo, int n) {
    int i = blockIdx.x * blockDim.x + threadIdx.x;
    if (i >= n) return;
    float f = w[i];
    unsigned short h = rne_bf16(f);
    float fh = __uint_as_float(((unsigned int)h) << 16);
    hi[i] = h;
    lo[i] = rne_bf16(f - fh);
}

// ---------- CSR build ----------
__global__ void hist_kernel(const int* __restrict__ row, int* __restrict__ cnt, int E) {
    int e = blockIdx.x * blockDim.x + threadIdx.x;
    if (e < E) atomicAdd(&cnt[row[e]], 1);
}

__global__ void scan1_kernel(const int* __restrict__ cnt, int* __restrict__ rowptr,
                             int* __restrict__ bsum, int N) {
    __shared__ int s[256];
    int tid = threadIdx.x;
    int gid = blockIdx.x * 256 + tid;
    int v = (gid < N) ? cnt[gid] : 0;
    s[tid] = v;
    __syncthreads();
    for (int off = 1; off < 256; off <<= 1) {
        int t = (tid >= off) ? s[tid - off] : 0;
        __syncthreads();
        s[tid] += t;
        __syncthreads();
    }
    if (gid < N) rowptr[gid] = s[tid] - v;
    if (tid == 255) bsum[blockIdx.x] = s[255];
}

__global__ void scan2_kernel(int* __restrict__ bsum, int* __restrict__ boff, int nb) {
    __shared__ int s[256];
    int tid = threadIdx.x;
    int v = (tid < nb) ? bsum[tid] : 0;
    s[tid] = v;
    __syncthreads();
    for (int off = 1; off < 256; off <<= 1) {
        int t = (tid >= off) ? s[tid - off] : 0;
        __syncthreads();
        s[tid] += t;
        __syncthreads();
    }
    if (tid < nb) boff[tid] = s[tid] - v;
}

__global__ void scan3_kernel(int* __restrict__ rowptr, const int* __restrict__ boff,
                             int* __restrict__ cursor, int N, int E) {
    int gid = blockIdx.x * 256 + threadIdx.x;
    if (gid < N) {
        int v = rowptr[gid] + boff[gid >> 8];
        rowptr[gid] = v;
        cursor[gid] = v;
    } else if (gid == N) {
        rowptr[N] = E;
    }
}

__global__ void scatter_kernel(const int* __restrict__ row, const int* __restrict__ col,
                               const float* __restrict__ ew, int* __restrict__ cursor,
                               int2* __restrict__ ep, int E) {
    int e = blockIdx.x * blockDim.x + threadIdx.x;
    if (e >= E) return;
    int p = atomicAdd(&cursor[row[e]], 1);
    ep[p] = make_int2(col[e], __float_as_int(ew[e]));
}

// ---------- fused layer: gather (into LDS) + MFMA GEMM ----------
__device__ inline void accum8(float* acc, uint4 a, float w) {
    acc[0] += __uint_as_float(a.x << 16) * w;
    acc[1] += __uint_as_float(a.x & 0xffff0000u) * w;
    acc[2] += __uint_as_float(a.y << 16) * w;
    acc[3] += __uint_as_float(a.y & 0xffff0000u) * w;
    acc[4] += __uint_as_float(a.z << 16) * w;
    acc[5] += __uint_as_float(a.z & 0xffff0000u) * w;
    acc[6] += __uint_as_float(a.w << 16) * w;
    acc[7] += __uint_as_float(a.w & 0xffff0000u) * w;
}

// y[N, 0:OUTR] = [src|mean_agg(src)](bf16) @ (Whi+Wlo)^T + b, opt relu.
// Block: 256 thr = 4 waves; block tile = 64 nodes; wave = 16 nodes (1 M-tile).
template<int OUTR, bool RELU, bool BF16OUT>
__global__ __launch_bounds__(256) void sage_fused(
    const unsigned short* __restrict__ src, const int* __restrict__ rowptr,
    const int2* __restrict__ ep,
    const unsigned short* __restrict__ Whi, const unsigned short* __restrict__ Wlo,
    const float* __restrict__ bias, float* __restrict__ outf,
    unsigned short* __restrict__ outb, int N) {
    constexpr int NT = OUTR / 16;
    __shared__ short sAgg[64][136];     // agg tile, bf16; stride 136 -> 2-way banks
    __shared__ short sW[2][OUTR][40];   // W hi/lo chunk;  stride 40  -> 2-way banks
    int tid = threadIdx.x;
    int wv = tid >> 6;
    int lane = tid & 63;
    int blk0 = blockIdx.x * 64;

    // ---- phase 1: gather 64 agg rows into LDS ----
    {
        int slot = lane >> 4;           // node sub-slot (4 per wave)
        int fl = lane & 15;             // 16B feature chunk within row
        for (int g = 0; g < 4; ++g) {
            int nl = wv * 16 + g * 4 + slot;
            int n = blk0 + nl;
            if (n >= N) continue;
            int beg = rowptr[n], end = rowptr[n + 1];
            float acc[8];
#pragma unroll
            for (int j = 0; j < 8; j++) acc[j] = 0.f;
            float ds = 0.f;
            int e = beg;
            for (; e + 7 < end; e += 8) {
                int2 p[8];
#pragma unroll
                for (int u = 0; u < 8; u++) p[u] = ep[e + u];
                uint4 a[8];
#pragma unroll
                for (int u = 0; u < 8; u++)
                    a[u] = *reinterpret_cast<const uint4*>(src + (size_t)p[u].x * D + fl * 8);
#pragma unroll
                for (int u = 0; u < 8; u++) {
                    float w = __int_as_float(p[u].y);
                    accum8(acc, a[u], w);
                    ds += w;
                }
            }
            for (; e + 3 < end; e += 4) {
                int2 p[4];
#pragma unroll
                for (int u = 0; u < 4; u++) p[u] = ep[e + u];
#pragma unroll
                for (int u = 0; u < 4; u++) {
                    uint4 a = *reinterpret_cast<const uint4*>(src + (size_t)p[u].x * D + fl * 8);
                    float w = __int_as_float(p[u].y);
                    accum8(acc, a, w);
                    ds += w;
                }
            }
            for (; e < end; ++e) {
                int2 p = ep[e];
                uint4 a = *reinterpret_cast<const uint4*>(src + (size_t)p.x * D + fl * 8);
                float w = __int_as_float(p.y);
                accum8(acc, a, w);
                ds += w;
            }
            float inv = 1.0f / (ds > 1.f ? ds : 1.f);
            uint4 o;
            o.x = (unsigned int)rne_bf16(acc[0] * inv) | ((unsigned int)rne_bf16(acc[1] * inv) << 16);
            o.y = (unsigned int)rne_bf16(acc[2] * inv) | ((unsigned int)rne_bf16(acc[3] * inv) << 16);
            o.z = (unsigned int)rne_bf16(acc[4] * inv) | ((unsigned int)rne_bf16(acc[5] * inv) << 16);
            o.w = (unsigned int)rne_bf16(acc[6] * inv) | ((unsigned int)rne_bf16(acc[7] * inv) << 16);
            *reinterpret_cast<uint4*>(&sAgg[nl][fl * 8]) = o;
        }
    }
    __syncthreads();

    // ---- phase 2: MFMA K-loop ----
    int nlane = lane & 15;
    int quad = lane >> 4;
    int m0 = blk0 + wv * 16;
    int rA = m0 + nlane; if (rA >= N) rA = N - 1;   // clamped; stores guarded
    const unsigned short* ax = src + (size_t)rA * D + quad * 8;

    floatx4 acc[NT];
#pragma unroll
    for (int nt = 0; nt < NT; nt++) acc[nt] = (floatx4){0.f, 0.f, 0.f, 0.f};

#pragma unroll
    for (int ks = 0; ks < 8; ks++) {
        int k0 = ks * 32;
        // A fragment: x-half from global, agg-half from LDS
        short8 a;
        if (k0 < D) a = *reinterpret_cast<const short8*>(ax + k0);
        else        a = *reinterpret_cast<const short8*>(&sAgg[wv * 16 + nlane][(k0 - D) + quad * 8]);
        // stage W hi+lo chunk (OUTR rows x 32 k each)
        for (int s = tid; s < OUTR * 8; s += 256) {
            int half = s / (OUTR * 4);
            int rem = s - half * (OUTR * 4);
            int row = rem >> 2, q = rem & 3;
            const unsigned short* wp = (half ? Wlo : Whi) + (size_t)row * K2 + k0 + q * 8;
            *reinterpret_cast<uint4*>(&sW[half][row][q * 8]) = *reinterpret_cast<const uint4*>(wp);
        }
        __syncthreads();
#pragma unroll
        for (int nt = 0; nt < NT; nt++) {
            short8 bh = *reinterpret_cast<const short8*>(&sW[0][nt * 16 + nlane][quad * 8]);
            short8 bl = *reinterpret_cast<const short8*>(&sW[1][nt * 16 + nlane][quad * 8]);
            acc[nt] = __builtin_amdgcn_mfma_f32_16x16x32_bf16(a, bh, acc[nt], 0, 0, 0);
            acc[nt] = __builtin_amdgcn_mfma_f32_16x16x32_bf16(a, bl, acc[nt], 0, 0, 0);
        }
        __syncthreads();
    }

    // ---- epilogue: C/D col=lane&15, row=quad*4+reg ----
#pragma unroll
    for (int nt = 0; nt < NT; nt++) {
        int c = nt * 16 + nlane;
        float bb = bias[c];
#pragma unroll
        for (int r = 0; r < 4; r++) {
            int node = m0 + quad * 4 + r;
            if (node < N) {
                float y = acc[nt][r] + bb;
                if (RELU) y = y > 0.f ? y : 0.f;
                if (BF16OUT) outb[(size_t)node * OUTR + c] = rne_bf16(y);
                else         outf[(size_t)node * OUTR + c] = y;
            }
        }
    }
}

extern "C" void kernel_launch(void* const* d_in, const int* in_sizes, int n_in,
                              void* d_out, int out_size, void* d_ws, size_t ws_size,
                              hipStream_t stream) {
    const float* x  = (const float*)d_in[0];
    const int*   ei = (const int*)d_in[1];
    const float* ew = (const float*)d_in[2];
    const float* W0 = (const float*)d_in[3];
    const float* b0 = (const float*)d_in[4];
    const float* W1 = (const float*)d_in[5];
    const float* b1 = (const float*)d_in[6];
    const float* W2 = (const float*)d_in[7];
    const float* b2 = (const float*)d_in[8];
    float* out = (float*)d_out;

    const int N = 50000;
    const int E = in_sizes[2];          // 800000
    const int* row = ei;
    const int* col = ei + E;

    char* base = (char*)d_ws;
    size_t ND = (size_t)N * D;
    unsigned short* x_hi   = (unsigned short*)base;               base += ND * 2;
    unsigned short* h0_hi  = (unsigned short*)base;               base += ND * 2;
    unsigned short* h1_hi  = (unsigned short*)base;               base += ND * 2;
    int2* ep               = (int2*)base;                         base += (size_t)E * 8;
    int* rowptr            = (int*)base;                          base += (size_t)(N + 1) * 4;
    unsigned short* W0hi   = (unsigned short*)base;               base += 128 * 256 * 2;
    unsigned short* W0lo   = (unsigned short*)base;               base += 128 * 256 * 2;
    unsigned short* W1hi   = (unsigned short*)base;               base += 128 * 256 * 2;
    unsigned short* W1lo   = (unsigned short*)base;               base += 128 * 256 * 2;
    unsigned short* W2hi   = (unsigned short*)base;               base += 64 * 256 * 2;
    unsigned short* W2lo   = (unsigned short*)base;               base += 64 * 256 * 2;

    int* cnt    = (int*)h0_hi;          // CSR scratch (dead until layer-0 GEMM)
    int* cursor = cnt + N;
    int* bsum   = cursor + N;
    int* boff   = bsum + 256;

    int nbScan = (N + 255) / 256;       // 196

    // ---- casts ----
    int n4 = (int)(ND / 4);
    cast_x_kernel<<<(n4 + 255) / 256, 256, 0, stream>>>(x, x_hi, n4);
    cast_w_kernel<<<(128 * 256 + 255) / 256, 256, 0, stream>>>(W0, W0hi, W0lo, 128 * 256);
    cast_w_kernel<<<(128 * 256 + 255) / 256, 256, 0, stream>>>(W1, W1hi, W1lo, 128 * 256);
    cast_w_kernel<<<(64 * 256 + 255) / 256, 256, 0, stream>>>(W2, W2hi, W2lo, 64 * 256);

    // ---- CSR build ----
    hipMemsetAsync(cnt, 0, (size_t)N * sizeof(int), stream);
    hist_kernel<<<(E + 255) / 256, 256, 0, stream>>>(row, cnt, E);
    scan1_kernel<<<nbScan, 256, 0, stream>>>(cnt, rowptr, bsum, N);
    scan2_kernel<<<1, 256, 0, stream>>>(bsum, boff, nbScan);
    scan3_kernel<<<(N + 256) / 256 + 1, 256, 0, stream>>>(rowptr, boff, cursor, N, E);
    scatter_kernel<<<(E + 255) / 256, 256, 0, stream>>>(row, col, ew, cursor, ep, E);

    int fusedBlocks = (N + 63) / 64;    // 782

    // layer 0: x -> h0
    sage_fused<128, true, true><<<fusedBlocks, 256, 0, stream>>>(
        x_hi, rowptr, ep, W0hi, W0lo, b0, nullptr, h0_hi, N);

    // layer 1: h0 -> h1
    sage_fused<128, true, true><<<fusedBlocks, 256, 0, stream>>>(
        h0_hi, rowptr, ep, W1hi, W1lo, b1, nullptr, h1_hi, N);

    // layer 2: h1 -> out (OUT=64, no relu, fp32)
    sage_fused<64, false, false><<<fusedBlocks, 256, 0, stream>>>(
        h1_hi, rowptr, ep, W2hi, W2lo, b2, out, nullptr, N);
}

// Round 9
// 351.003 us; speedup vs baseline: 1.0726x; 1.0726x over previous
//
#include <hip/hip_runtime.h>

// GraphSAGE 3-layer, N=50000, E=800000, D=128, D_OUT=64.
// R9: revert R8 fusion (regressed). Split gather (R7, unroll x8) + new GEMM:
// whole-K W hi+lo for a 32-col slice resident in LDS (stride 260 shorts,
// <=2-way banks), ONE barrier, 16 A-frag loads issued up front per wave,
// 64 MFMAs from LDS with no re-staging.

#define D 128
#define K2 256

typedef __attribute__((ext_vector_type(8))) short short8;
typedef __attribute__((ext_vector_type(4))) float floatx4;

__device__ inline unsigned short rne_bf16(float f) {
    unsigned int u = __float_as_uint(f);
    u += 0x7fffu + ((u >> 16) & 1u);
    return (unsigned short)(u >> 16);
}

// ---------- casts ----------
__global__ void cast_x_kernel(const float* __restrict__ in, unsigned short* __restrict__ out, int n4) {
    int i = blockIdx.x * blockDim.x + threadIdx.x;
    if (i >= n4) return;
    float4 v = reinterpret_cast<const float4*>(in)[i];
    ushort4 o;
    o.x = rne_bf16(v.x); o.y = rne_bf16(v.y); o.z = rne_bf16(v.z); o.w = rne_bf16(v.w);
    reinterpret_cast<ushort4*>(out)[i] = o;
}

__global__ void cast_w_kernel(const float* __restrict__ w, unsigned short* __restrict__ hi,
                              unsigned short* __restrict__ lo, int n) {
    int i = blockIdx.x * blockDim.x + threadIdx.x;
    if (i >= n) return;
    float f = w[i];
    unsigned short h = rne_bf16(f);
    float fh = __uint_as_float(((unsigned int)h) << 16);
    hi[i] = h;
    lo[i] = rne_bf16(f - fh);
}

// ---------- CSR build ----------
__global__ void hist_kernel(const int* __restrict__ row, int* __restrict__ cnt, int E) {
    int e = blockIdx.x * blockDim.x + threadIdx.x;
    if (e < E) atomicAdd(&cnt[row[e]], 1);
}

__global__ void scan1_kernel(const int* __restrict__ cnt, int* __restrict__ rowptr,
                             int* __restrict__ bsum, int N) {
    __shared__ int s[256];
    int tid = threadIdx.x;
    int gid = blockIdx.x * 256 + tid;
    int v = (gid < N) ? cnt[gid] : 0;
    s[tid] = v;
    __syncthreads();
    for (int off = 1; off < 256; off <<= 1) {
        int t = (tid >= off) ? s[tid - off] : 0;
        __syncthreads();
        s[tid] += t;
        __syncthreads();
    }
    if (gid < N) rowptr[gid] = s[tid] - v;
    if (tid == 255) bsum[blockIdx.x] = s[255];
}

__global__ void scan2_kernel(int* __restrict__ bsum, int* __restrict__ boff, int nb) {
    __shared__ int s[256];
    int tid = threadIdx.x;
    int v = (tid < nb) ? bsum[tid] : 0;
    s[tid] = v;
    __syncthreads();
    for (int off = 1; off < 256; off <<= 1) {
        int t = (tid >= off) ? s[tid - off] : 0;
        __syncthreads();
        s[tid] += t;
        __syncthreads();
    }
    if (tid < nb) boff[tid] = s[tid] - v;
}

__global__ void scan3_kernel(int* __restrict__ rowptr, const int* __restrict__ boff,
                             int* __restrict__ cursor, int N, int E) {
    int gid = blockIdx.x * 256 + threadIdx.x;
    if (gid < N) {
        int v = rowptr[gid] + boff[gid >> 8];
        rowptr[gid] = v;
        cursor[gid] = v;
    } else if (gid == N) {
        rowptr[N] = E;
    }
}

__global__ void scatter_kernel(const int* __restrict__ row, const int* __restrict__ col,
                               const float* __restrict__ ew, int* __restrict__ cursor,
                               int2* __restrict__ ep, int E) {
    int e = blockIdx.x * blockDim.x + threadIdx.x;
    if (e >= E) return;
    int p = atomicAdd(&cursor[row[e]], 1);
    ep[p] = make_int2(col[e], __float_as_int(ew[e]));
}

// ---------- gather aggregation (bf16 src/dst), unroll x8 ----------
__device__ inline void accum8(float* acc, uint4 a, float w) {
    acc[0] += __uint_as_float(a.x << 16) * w;
    acc[1] += __uint_as_float(a.x & 0xffff0000u) * w;
    acc[2] += __uint_as_float(a.y << 16) * w;
    acc[3] += __uint_as_float(a.y & 0xffff0000u) * w;
    acc[4] += __uint_as_float(a.z << 16) * w;
    acc[5] += __uint_as_float(a.z & 0xffff0000u) * w;
    acc[6] += __uint_as_float(a.w << 16) * w;
    acc[7] += __uint_as_float(a.w & 0xffff0000u) * w;
}

__global__ void gather_agg_bf(const unsigned short* __restrict__ src, const int* __restrict__ rowptr,
                              const int2* __restrict__ ep, unsigned short* __restrict__ agg, int N) {
    long long t = (long long)blockIdx.x * blockDim.x + threadIdx.x;
    int wid = (int)(t >> 6);
    int lane = threadIdx.x & 63;
    int slot = lane >> 4;
    int fl = lane & 15;
    int n = wid * 4 + slot;
    if (n >= N) return;
    int beg = rowptr[n], end = rowptr[n + 1];
    float acc[8];
#pragma unroll
    for (int j = 0; j < 8; j++) acc[j] = 0.f;
    float ds = 0.f;
    int e = beg;
    for (; e + 7 < end; e += 8) {
        int2 p[8];
#pragma unroll
        for (int u = 0; u < 8; u++) p[u] = ep[e + u];
        uint4 a[8];
#pragma unroll
        for (int u = 0; u < 8; u++)
            a[u] = *reinterpret_cast<const uint4*>(src + (size_t)p[u].x * D + fl * 8);
#pragma unroll
        for (int u = 0; u < 8; u++) {
            float w = __int_as_float(p[u].y);
            accum8(acc, a[u], w);
            ds += w;
        }
    }
    for (; e + 3 < end; e += 4) {
        int2 p[4];
#pragma unroll
        for (int u = 0; u < 4; u++) p[u] = ep[e + u];
#pragma unroll
        for (int u = 0; u < 4; u++) {
            uint4 a = *reinterpret_cast<const uint4*>(src + (size_t)p[u].x * D + fl * 8);
            float w = __int_as_float(p[u].y);
            accum8(acc, a, w);
            ds += w;
        }
    }
    for (; e < end; ++e) {
        int2 p = ep[e];
        uint4 a = *reinterpret_cast<const uint4*>(src + (size_t)p.x * D + fl * 8);
        float w = __int_as_float(p.y);
        accum8(acc, a, w);
        ds += w;
    }
    float inv = 1.0f / (ds > 1.f ? ds : 1.f);
    uint4 o;
    o.x = (unsigned int)rne_bf16(acc[0] * inv) | ((unsigned int)rne_bf16(acc[1] * inv) << 16);
    o.y = (unsigned int)rne_bf16(acc[2] * inv) | ((unsigned int)rne_bf16(acc[3] * inv) << 16);
    o.z = (unsigned int)rne_bf16(acc[4] * inv) | ((unsigned int)rne_bf16(acc[5] * inv) << 16);
    o.w = (unsigned int)rne_bf16(acc[6] * inv) | ((unsigned int)rne_bf16(acc[7] * inv) << 16);
    *reinterpret_cast<uint4*>(agg + (size_t)n * D + fl * 8) = o;
}

// ---------- MFMA GEMM, whole-K W slice in LDS, one barrier ----------
// y[N, c0:c0+32] = [x|agg](bf16) @ (Whi+Wlo)[c0:c0+32,:]^T + b
// Block: 256 thr = 4 waves; block tile = 128 nodes x 32 cols; wave = 32 nodes.
// sW[2][32][260]: stride 260 shorts = 130 words = 2 mod 32 -> B-frag reads
// (16 rows x b128) hit distinct bank pairs, <=2-way everywhere (free).
// A-frag: A[m=lane&15][k=quad*8+j] -> 16B global loads, all 16 issued upfront.
// C/D: col=lane&15, row=quad*4+reg (verified m89).
template<bool RELU, bool BF16OUT, int OSTRIDE>
__global__ __launch_bounds__(256) void sage_gemm(
    const unsigned short* __restrict__ src, const unsigned short* __restrict__ agg,
    const unsigned short* __restrict__ Whi, const unsigned short* __restrict__ Wlo,
    const float* __restrict__ bias, float* __restrict__ outf,
    unsigned short* __restrict__ outb, int N) {
    __shared__ short sW[2][32][260];
    int tid = threadIdx.x;
    int c0 = blockIdx.y * 32;

    // stage whole-K W hi+lo for 32 cols: 2048 uint4 slots, 8 per thread.
    // r varies fastest across lanes -> write banks 2r mod 32, 2-way, free.
    for (int i = tid; i < 2048; i += 256) {
        int h = i >> 10;
        int rem = i & 1023;
        int r = rem & 31;
        int k8 = rem >> 5;
        const unsigned short* wp = (h ? Wlo : Whi) + (size_t)(c0 + r) * K2 + k8 * 8;
        *reinterpret_cast<uint4*>(&sW[h][r][k8 * 8]) = *reinterpret_cast<const uint4*>(wp);
    }
    __syncthreads();

    int lane = tid & 63;
    int wv = tid >> 6;
    int nlane = lane & 15;
    int quad = lane >> 4;
    int m0 = blockIdx.x * 128 + wv * 32;
    int r0 = m0 + nlane;      if (r0 >= N) r0 = N - 1;   // clamped; stores guarded
    int r1 = m0 + 16 + nlane; if (r1 >= N) r1 = N - 1;

    // all 16 A-fragment loads issued up front
    short8 a[2][8];
#pragma unroll
    for (int ks = 0; ks < 8; ks++) {
        int k0 = ks * 32;
        const unsigned short* p0 = (k0 < D) ? (src + (size_t)r0 * D + k0)
                                            : (agg + (size_t)r0 * D + (k0 - D));
        const unsigned short* p1 = (k0 < D) ? (src + (size_t)r1 * D + k0)
                                            : (agg + (size_t)r1 * D + (k0 - D));
        a[0][ks] = *reinterpret_cast<const short8*>(p0 + quad * 8);
        a[1][ks] = *reinterpret_cast<const short8*>(p1 + quad * 8);
    }

    floatx4 acc[2][2];
#pragma unroll
    for (int mt = 0; mt < 2; mt++)
#pragma unroll
        for (int nt = 0; nt < 2; nt++) acc[mt][nt] = (floatx4){0.f, 0.f, 0.f, 0.f};

#pragma unroll
    for (int ks = 0; ks < 8; ks++) {
        int k0 = ks * 32;
#pragma unroll
        for (int nt = 0; nt < 2; nt++) {
            short8 bh = *reinterpret_cast<const short8*>(&sW[0][nt * 16 + nlane][k0 + quad * 8]);
            short8 bl = *reinterpret_cast<const short8*>(&sW[1][nt * 16 + nlane][k0 + quad * 8]);
            acc[0][nt] = __builtin_amdgcn_mfma_f32_16x16x32_bf16(a[0][ks], bh, acc[0][nt], 0, 0, 0);
            acc[0][nt] = __builtin_amdgcn_mfma_f32_16x16x32_bf16(a[0][ks], bl, acc[0][nt], 0, 0, 0);
            acc[1][nt] = __builtin_amdgcn_mfma_f32_16x16x32_bf16(a[1][ks], bh, acc[1][nt], 0, 0, 0);
            acc[1][nt] = __builtin_amdgcn_mfma_f32_16x16x32_bf16(a[1][ks], bl, acc[1][nt], 0, 0, 0);
        }
    }

#pragma unroll
    for (int nt = 0; nt < 2; nt++) {
        int c = c0 + nt * 16 + nlane;
        float bb = bias[c];
#pragma unroll
        for (int mt = 0; mt < 2; mt++) {
#pragma unroll
            for (int r = 0; r < 4; r++) {
                int node = m0 + mt * 16 + quad * 4 + r;
                if (node < N) {
                    float y = acc[mt][nt][r] + bb;
                    if (RELU) y = y > 0.f ? y : 0.f;
                    if (BF16OUT) outb[(size_t)node * OSTRIDE + c] = rne_bf16(y);
                    else         outf[(size_t)node * OSTRIDE + c] = y;
                }
            }
        }
    }
}

extern "C" void kernel_launch(void* const* d_in, const int* in_sizes, int n_in,
                              void* d_out, int out_size, void* d_ws, size_t ws_size,
                              hipStream_t stream) {
    const float* x  = (const float*)d_in[0];
    const int*   ei = (const int*)d_in[1];
    const float* ew = (const float*)d_in[2];
    const float* W0 = (const float*)d_in[3];
    const float* b0 = (const float*)d_in[4];
    const float* W1 = (const float*)d_in[5];
    const float* b1 = (const float*)d_in[6];
    const float* W2 = (const float*)d_in[7];
    const float* b2 = (const float*)d_in[8];
    float* out = (float*)d_out;

    const int N = 50000;
    const int E = in_sizes[2];          // 800000
    const int* row = ei;
    const int* col = ei + E;

    char* base = (char*)d_ws;
    size_t ND = (size_t)N * D;
    unsigned short* x_hi   = (unsigned short*)base;               base += ND * 2;
    unsigned short* h0_hi  = (unsigned short*)base;               base += ND * 2;
    unsigned short* h1_hi  = (unsigned short*)base;               base += ND * 2;
    unsigned short* agg_hi = (unsigned short*)base;               base += ND * 2;
    int2* ep               = (int2*)base;                         base += (size_t)E * 8;
    int* rowptr            = (int*)base;                          base += (size_t)(N + 1) * 4;
    unsigned short* W0hi   = (unsigned short*)base;               base += 128 * 256 * 2;
    unsigned short* W0lo   = (unsigned short*)base;               base += 128 * 256 * 2;
    unsigned short* W1hi   = (unsigned short*)base;               base += 128 * 256 * 2;
    unsigned short* W1lo   = (unsigned short*)base;               base += 128 * 256 * 2;
    unsigned short* W2hi   = (unsigned short*)base;               base += 64 * 256 * 2;
    unsigned short* W2lo   = (unsigned short*)base;               base += 64 * 256 * 2;

    int* cnt    = (int*)h0_hi;          // CSR scratch (dead until layer-0 GEMM)
    int* cursor = cnt + N;
    int* bsum   = cursor + N;
    int* boff   = bsum + 256;

    int nbScan = (N + 255) / 256;       // 196

    // ---- casts ----
    int n4 = (int)(ND / 4);
    cast_x_kernel<<<(n4 + 255) / 256, 256, 0, stream>>>(x, x_hi, n4);
    cast_w_kernel<<<(128 * 256 + 255) / 256, 256, 0, stream>>>(W0, W0hi, W0lo, 128 * 256);
    cast_w_kernel<<<(128 * 256 + 255) / 256, 256, 0, stream>>>(W1, W1hi, W1lo, 128 * 256);
    cast_w_kernel<<<(64 * 256 + 255) / 256, 256, 0, stream>>>(W2, W2hi, W2lo, 64 * 256);

    // ---- CSR build ----
    hipMemsetAsync(cnt, 0, (size_t)N * sizeof(int), stream);
    hist_kernel<<<(E + 255) / 256, 256, 0, stream>>>(row, cnt, E);
    scan1_kernel<<<nbScan, 256, 0, stream>>>(cnt, rowptr, bsum, N);
    scan2_kernel<<<1, 256, 0, stream>>>(bsum, boff, nbScan);
    scan3_kernel<<<(N + 256) / 256 + 1, 256, 0, stream>>>(rowptr, boff, cursor, N, E);
    scatter_kernel<<<(E + 255) / 256, 256, 0, stream>>>(row, col, ew, cursor, ep, E);

    int nWaves = (N + 3) / 4;                       // 12500 (4 nodes/wave)
    int aggBlocks = (int)(((long long)nWaves * 64 + 255) / 256);
    int nodeTiles = (N + 127) / 128;                // 391
    dim3 g128(nodeTiles, 4);                        // OUT=128: four 32-col tiles
    dim3 g64(nodeTiles, 2);                         // OUT=64:  two 32-col tiles

    // layer 0: x -> h0
    gather_agg_bf<<<aggBlocks, 256, 0, stream>>>(x_hi, rowptr, ep, agg_hi, N);
    sage_gemm<true, true, D><<<g128, 256, 0, stream>>>(
        x_hi, agg_hi, W0hi, W0lo, b0, nullptr, h0_hi, N);

    // layer 1: h0 -> h1
    gather_agg_bf<<<aggBlocks, 256, 0, stream>>>(h0_hi, rowptr, ep, agg_hi, N);
    sage_gemm<true, true, D><<<g128, 256, 0, stream>>>(
        h0_hi, agg_hi, W1hi, W1lo, b1, nullptr, h1_hi, N);

    // layer 2: h1 -> out (OUT=64, no relu, fp32)
    gather_agg_bf<<<aggBlocks, 256, 0, stream>>>(h1_hi, rowptr, ep, agg_hi, N);
    sage_gemm<false, false, 64><<<g64, 256, 0, stream>>>(
        h1_hi, agg_hi, W2hi, W2lo, b2, out, nullptr, N);
}

// Round 10
// 342.887 us; speedup vs baseline: 1.0979x; 1.0237x over previous
//
#include <hip/hip_runtime.h>

// GraphSAGE 3-layer, N=50000, E=800000, D=128, D_OUT=64.
// R10: scatter -> XCD-affine range-partitioned (16 node ranges; blocks with
// blockIdx%16==r serve range r, so ep-region stores stay in one XCD's L2 and
// write back once). cast_w x3 fused. Gather/GEMM unchanged from R9.

#define D 128
#define K2 256

typedef __attribute__((ext_vector_type(8))) short short8;
typedef __attribute__((ext_vector_type(4))) float floatx4;

__device__ inline unsigned short rne_bf16(float f) {
    unsigned int u = __float_as_uint(f);
    u += 0x7fffu + ((u >> 16) & 1u);
    return (unsigned short)(u >> 16);
}

// ---------- casts ----------
__global__ void cast_x_kernel(const float* __restrict__ in, unsigned short* __restrict__ out, int n4) {
    int i = blockIdx.x * blockDim.x + threadIdx.x;
    if (i >= n4) return;
    float4 v = reinterpret_cast<const float4*>(in)[i];
    ushort4 o;
    o.x = rne_bf16(v.x); o.y = rne_bf16(v.y); o.z = rne_bf16(v.z); o.w = rne_bf16(v.w);
    reinterpret_cast<ushort4*>(out)[i] = o;
}

// all three weight matrices in one launch (saves 2 dispatches)
__global__ void cast_w_all(const float* __restrict__ W0, const float* __restrict__ W1,
                           const float* __restrict__ W2,
                           unsigned short* __restrict__ h0, unsigned short* __restrict__ l0,
                           unsigned short* __restrict__ h1, unsigned short* __restrict__ l1,
                           unsigned short* __restrict__ h2, unsigned short* __restrict__ l2) {
    int i = blockIdx.x * blockDim.x + threadIdx.x;
    const float* w; unsigned short *hi, *lo; int idx;
    if (i < 32768)      { w = W0; hi = h0; lo = l0; idx = i; }
    else if (i < 65536) { w = W1; hi = h1; lo = l1; idx = i - 32768; }
    else if (i < 81920) { w = W2; hi = h2; lo = l2; idx = i - 65536; }
    else return;
    float f = w[idx];
    unsigned short h = rne_bf16(f);
    float fh = __uint_as_float(((unsigned int)h) << 16);
    hi[idx] = h;
    lo[idx] = rne_bf16(f - fh);
}

// ---------- CSR build ----------
__global__ void hist_kernel(const int* __restrict__ row, int* __restrict__ cnt, int E) {
    int e = blockIdx.x * blockDim.x + threadIdx.x;
    if (e < E) atomicAdd(&cnt[row[e]], 1);
}

__global__ void scan1_kernel(const int* __restrict__ cnt, int* __restrict__ rowptr,
                             int* __restrict__ bsum, int N) {
    __shared__ int s[256];
    int tid = threadIdx.x;
    int gid = blockIdx.x * 256 + tid;
    int v = (gid < N) ? cnt[gid] : 0;
    s[tid] = v;
    __syncthreads();
    for (int off = 1; off < 256; off <<= 1) {
        int t = (tid >= off) ? s[tid - off] : 0;
        __syncthreads();
        s[tid] += t;
        __syncthreads();
    }
    if (gid < N) rowptr[gid] = s[tid] - v;
    if (tid == 255) bsum[blockIdx.x] = s[255];
}

__global__ void scan2_kernel(int* __restrict__ bsum, int* __restrict__ boff, int nb) {
    __shared__ int s[256];
    int tid = threadIdx.x;
    int v = (tid < nb) ? bsum[tid] : 0;
    s[tid] = v;
    __syncthreads();
    for (int off = 1; off < 256; off <<= 1) {
        int t = (tid >= off) ? s[tid - off] : 0;
        __syncthreads();
        s[tid] += t;
        __syncthreads();
    }
    if (tid < nb) boff[tid] = s[tid] - v;
}

__global__ void scan3_kernel(int* __restrict__ rowptr, const int* __restrict__ boff,
                             int* __restrict__ cursor, int N, int E) {
    int gid = blockIdx.x * 256 + threadIdx.x;
    if (gid < N) {
        int v = rowptr[gid] + boff[gid >> 8];
        rowptr[gid] = v;
        cursor[gid] = v;
    } else if (gid == N) {
        rowptr[N] = E;
    }
}

// Range-partitioned scatter: 16 node ranges of 3125. Block b serves range
// r = b%16 (presumed XCD b%8 => all stores to range r's ep region come from
// one XCD; region ~400KB stays L2-resident, single writeback). b>>4 picks the
// edge chunk. Correctness independent of the XCD mapping.
__global__ void scatter_ranged(const int* __restrict__ row, const int* __restrict__ col,
                               const float* __restrict__ ew, int* __restrict__ cursor,
                               int2* __restrict__ ep, int E) {
    int b = blockIdx.x;
    int r = b & 15;
    int q = b >> 4;
    int nchunk = gridDim.x >> 4;
    int chunk = (E + nchunk - 1) / nchunk;
    int e0 = q * chunk;
    int e1 = e0 + chunk; if (e1 > E) e1 = E;
    int lo = r * 3125, hi = lo + 3125;
    for (int e = e0 + (int)threadIdx.x; e < e1; e += (int)blockDim.x) {
        int rw = row[e];
        if (rw >= lo && rw < hi) {
            int p = atomicAdd(&cursor[rw], 1);
            ep[p] = make_int2(col[e], __float_as_int(ew[e]));
        }
    }
}

// ---------- gather aggregation (bf16 src/dst), unroll x8 ----------
__device__ inline void accum8(float* acc, uint4 a, float w) {
    acc[0] += __uint_as_float(a.x << 16) * w;
    acc[1] += __uint_as_float(a.x & 0xffff0000u) * w;
    acc[2] += __uint_as_float(a.y << 16) * w;
    acc[3] += __uint_as_float(a.y & 0xffff0000u) * w;
    acc[4] += __uint_as_float(a.z << 16) * w;
    acc[5] += __uint_as_float(a.z & 0xffff0000u) * w;
    acc[6] += __uint_as_float(a.w << 16) * w;
    acc[7] += __uint_as_float(a.w & 0xffff0000u) * w;
}

__global__ void gather_agg_bf(const unsigned short* __restrict__ src, const int* __restrict__ rowptr,
                              const int2* __restrict__ ep, unsigned short* __restrict__ agg, int N) {
    long long t = (long long)blockIdx.x * blockDim.x + threadIdx.x;
    int wid = (int)(t >> 6);
    int lane = threadIdx.x & 63;
    int slot = lane >> 4;
    int fl = lane & 15;
    int n = wid * 4 + slot;
    if (n >= N) return;
    int beg = rowptr[n], end = rowptr[n + 1];
    float acc[8];
#pragma unroll
    for (int j = 0; j < 8; j++) acc[j] = 0.f;
    float ds = 0.f;
    int e = beg;
    for (; e + 7 < end; e += 8) {
        int2 p[8];
#pragma unroll
        for (int u = 0; u < 8; u++) p[u] = ep[e + u];
        uint4 a[8];
#pragma unroll
        for (int u = 0; u < 8; u++)
            a[u] = *reinterpret_cast<const uint4*>(src + (size_t)p[u].x * D + fl * 8);
#pragma unroll
        for (int u = 0; u < 8; u++) {
            float w = __int_as_float(p[u].y);
            accum8(acc, a[u], w);
            ds += w;
        }
    }
    for (; e + 3 < end; e += 4) {
        int2 p[4];
#pragma unroll
        for (int u = 0; u < 4; u++) p[u] = ep[e + u];
#pragma unroll
        for (int u = 0; u < 4; u++) {
            uint4 a = *reinterpret_cast<const uint4*>(src + (size_t)p[u].x * D + fl * 8);
            float w = __int_as_float(p[u].y);
            accum8(acc, a, w);
            ds += w;
        }
    }
    for (; e < end; ++e) {
        int2 p = ep[e];
        uint4 a = *reinterpret_cast<const uint4*>(src + (size_t)p.x * D + fl * 8);
        float w = __int_as_float(p.y);
        accum8(acc, a, w);
        ds += w;
    }
    float inv = 1.0f / (ds > 1.f ? ds : 1.f);
    uint4 o;
    o.x = (unsigned int)rne_bf16(acc[0] * inv) | ((unsigned int)rne_bf16(acc[1] * inv) << 16);
    o.y = (unsigned int)rne_bf16(acc[2] * inv) | ((unsigned int)rne_bf16(acc[3] * inv) << 16);
    o.z = (unsigned int)rne_bf16(acc[4] * inv) | ((unsigned int)rne_bf16(acc[5] * inv) << 16);
    o.w = (unsigned int)rne_bf16(acc[6] * inv) | ((unsigned int)rne_bf16(acc[7] * inv) << 16);
    *reinterpret_cast<uint4*>(agg + (size_t)n * D + fl * 8) = o;
}

// ---------- MFMA GEMM, whole-K W slice in LDS, one barrier ----------
// y[N, c0:c0+32] = [x|agg](bf16) @ (Whi+Wlo)[c0:c0+32,:]^T + b
// Block: 256 thr = 4 waves; tile = 128 nodes x 32 cols; wave = 32 nodes.
// sW stride 260 shorts -> <=2-way banks everywhere. A-frags loaded upfront.
template<bool RELU, bool BF16OUT, int OSTRIDE>
__global__ __launch_bounds__(256) void sage_gemm(
    const unsigned short* __restrict__ src, const unsigned short* __restrict__ agg,
    const unsigned short* __restrict__ Whi, const unsigned short* __restrict__ Wlo,
    const float* __restrict__ bias, float* __restrict__ outf,
    unsigned short* __restrict__ outb, int N) {
    __shared__ short sW[2][32][260];
    int tid = threadIdx.x;
    int c0 = blockIdx.y * 32;

    for (int i = tid; i < 2048; i += 256) {
        int h = i >> 10;
        int rem = i & 1023;
        int r = rem & 31;
        int k8 = rem >> 5;
        const unsigned short* wp = (h ? Wlo : Whi) + (size_t)(c0 + r) * K2 + k8 * 8;
        *reinterpret_cast<uint4*>(&sW[h][r][k8 * 8]) = *reinterpret_cast<const uint4*>(wp);
    }
    __syncthreads();

    int lane = tid & 63;
    int wv = tid >> 6;
    int nlane = lane & 15;
    int quad = lane >> 4;
    int m0 = blockIdx.x * 128 + wv * 32;
    int r0 = m0 + nlane;      if (r0 >= N) r0 = N - 1;   // clamped; stores guarded
    int r1 = m0 + 16 + nlane; if (r1 >= N) r1 = N - 1;

    short8 a[2][8];
#pragma unroll
    for (int ks = 0; ks < 8; ks++) {
        int k0 = ks * 32;
        const unsigned short* p0 = (k0 < D) ? (src + (size_t)r0 * D + k0)
                                            : (agg + (size_t)r0 * D + (k0 - D));
        const unsigned short* p1 = (k0 < D) ? (src + (size_t)r1 * D + k0)
                                            : (agg + (size_t)r1 * D + (k0 - D));
        a[0][ks] = *reinterpret_cast<const short8*>(p0 + quad * 8);
        a[1][ks] = *reinterpret_cast<const short8*>(p1 + quad * 8);
    }

    floatx4 acc[2][2];
#pragma unroll
    for (int mt = 0; mt < 2; mt++)
#pragma unroll
        for (int nt = 0; nt < 2; nt++) acc[mt][nt] = (floatx4){0.f, 0.f, 0.f, 0.f};

#pragma unroll
    for (int ks = 0; ks < 8; ks++) {
        int k0 = ks * 32;
#pragma unroll
        for (int nt = 0; nt < 2; nt++) {
            short8 bh = *reinterpret_cast<const short8*>(&sW[0][nt * 16 + nlane][k0 + quad * 8]);
            short8 bl = *reinterpret_cast<const short8*>(&sW[1][nt * 16 + nlane][k0 + quad * 8]);
            acc[0][nt] = __builtin_amdgcn_mfma_f32_16x16x32_bf16(a[0][ks], bh, acc[0][nt], 0, 0, 0);
            acc[0][nt] = __builtin_amdgcn_mfma_f32_16x16x32_bf16(a[0][ks], bl, acc[0][nt], 0, 0, 0);
            acc[1][nt] = __builtin_amdgcn_mfma_f32_16x16x32_bf16(a[1][ks], bh, acc[1][nt], 0, 0, 0);
            acc[1][nt] = __builtin_amdgcn_mfma_f32_16x16x32_bf16(a[1][ks], bl, acc[1][nt], 0, 0, 0);
        }
    }

#pragma unroll
    for (int nt = 0; nt < 2; nt++) {
        int c = c0 + nt * 16 + nlane;
        float bb = bias[c];
#pragma unroll
        for (int mt = 0; mt < 2; mt++) {
#pragma unroll
            for (int r = 0; r < 4; r++) {
                int node = m0 + mt * 16 + quad * 4 + r;
                if (node < N) {
                    float y = acc[mt][nt][r] + bb;
                    if (RELU) y = y > 0.f ? y : 0.f;
                    if (BF16OUT) outb[(size_t)node * OSTRIDE + c] = rne_bf16(y);
                    else         outf[(size_t)node * OSTRIDE + c] = y;
                }
            }
        }
    }
}

extern "C" void kernel_launch(void* const* d_in, const int* in_sizes, int n_in,
                              void* d_out, int out_size, void* d_ws, size_t ws_size,
                              hipStream_t stream) {
    const float* x  = (const float*)d_in[0];
    const int*   ei = (const int*)d_in[1];
    const float* ew = (const float*)d_in[2];
    const float* W0 = (const float*)d_in[3];
    const float* b0 = (const float*)d_in[4];
    const float* W1 = (const float*)d_in[5];
    const float* b1 = (const float*)d_in[6];
    const float* W2 = (const float*)d_in[7];
    const float* b2 = (const float*)d_in[8];
    float* out = (float*)d_out;

    const int N = 50000;
    const int E = in_sizes[2];          // 800000
    const int* row = ei;
    const int* col = ei + E;

    char* base = (char*)d_ws;
    size_t ND = (size_t)N * D;
    unsigned short* x_hi   = (unsigned short*)base;               base += ND * 2;
    unsigned short* h0_hi  = (unsigned short*)base;               base += ND * 2;
    unsigned short* h1_hi  = (unsigned short*)base;               base += ND * 2;
    unsigned short* agg_hi = (unsigned short*)base;               base += ND * 2;
    int2* ep               = (int2*)base;                         base += (size_t)E * 8;
    int* rowptr            = (int*)base;                          base += (size_t)(N + 1) * 4;
    unsigned short* W0hi   = (unsigned short*)base;               base += 128 * 256 * 2;
    unsigned short* W0lo   = (unsigned short*)base;               base += 128 * 256 * 2;
    unsigned short* W1hi   = (unsigned short*)base;               base += 128 * 256 * 2;
    unsigned short* W1lo   = (unsigned short*)base;               base += 128 * 256 * 2;
    unsigned short* W2hi   = (unsigned short*)base;               base += 64 * 256 * 2;
    unsigned short* W2lo   = (unsigned short*)base;               base += 64 * 256 * 2;

    int* cnt    = (int*)h0_hi;          // CSR scratch (dead until layer-0 GEMM)
    int* cursor = cnt + N;
    int* bsum   = cursor + N;
    int* boff   = bsum + 256;

    int nbScan = (N + 255) / 256;       // 196

    // ---- casts ----
    int n4 = (int)(ND / 4);
    cast_x_kernel<<<(n4 + 255) / 256, 256, 0, stream>>>(x, x_hi, n4);
    cast_w_all<<<(81920 + 255) / 256, 256, 0, stream>>>(W0, W1, W2,
        W0hi, W0lo, W1hi, W1lo, W2hi, W2lo);

    // ---- CSR build ----
    hipMemsetAsync(cnt, 0, (size_t)N * sizeof(int), stream);
    hist_kernel<<<(E + 255) / 256, 256, 0, stream>>>(row, cnt, E);
    scan1_kernel<<<nbScan, 256, 0, stream>>>(cnt, rowptr, bsum, N);
    scan2_kernel<<<1, 256, 0, stream>>>(bsum, boff, nbScan);
    scan3_kernel<<<(N + 256) / 256 + 1, 256, 0, stream>>>(rowptr, boff, cursor, N, E);
    scatter_ranged<<<2048, 256, 0, stream>>>(row, col, ew, cursor, ep, E);

    int nWaves = (N + 3) / 4;                       // 12500 (4 nodes/wave)
    int aggBlocks = (int)(((long long)nWaves * 64 + 255) / 256);
    int nodeTiles = (N + 127) / 128;                // 391
    dim3 g128(nodeTiles, 4);                        // OUT=128: four 32-col tiles
    dim3 g64(nodeTiles, 2);                         // OUT=64:  two 32-col tiles

    // layer 0: x -> h0
    gather_agg_bf<<<aggBlocks, 256, 0, stream>>>(x_hi, rowptr, ep, agg_hi, N);
    sage_gemm<true, true, D><<<g128, 256, 0, stream>>>(
        x_hi, agg_hi, W0hi, W0lo, b0, nullptr, h0_hi, N);

    // layer 1: h0 -> h1
    gather_agg_bf<<<aggBlocks, 256, 0, stream>>>(h0_hi, rowptr, ep, agg_hi, N);
    sage_gemm<true, true, D><<<g128, 256, 0, stream>>>(
        h0_hi, agg_hi, W1hi, W1lo, b1, nullptr, h1_hi, N);

    // layer 2: h1 -> out (OUT=64, no relu, fp32)
    gather_agg_bf<<<aggBlocks, 256, 0, stream>>>(h1_hi, rowptr, ep, agg_hi, N);
    sage_gemm<false, false, 64><<<g64, 256, 0, stream>>>(
        h1_hi, agg_hi, W2hi, W2lo, b2, out, nullptr, N);
}

// Round 11
// 333.335 us; speedup vs baseline: 1.1294x; 1.0287x over previous
//
#include <hip/hip_runtime.h>

// GraphSAGE 3-layer, N=50000, E=800000, D=128, D_OUT=64.
// R11: quarter-ordered CSR (key = node*4 + col-quarter) so co-resident gather
// waves sweep one 3.2MB src slice at a time (fits per-XCD L2). Scatter with 8
// dst ranges. cast_x+cast_w+hist merged into one prep kernel. GEMM unchanged.

#define D 128
#define K2 256
#define NQ 4            // col quarters
#define QW 12500        // quarter width (N/4)

typedef __attribute__((ext_vector_type(8))) short short8;
typedef __attribute__((ext_vector_type(4))) float floatx4;

__device__ inline unsigned short rne_bf16(float f) {
    unsigned int u = __float_as_uint(f);
    u += 0x7fffu + ((u >> 16) & 1u);
    return (unsigned short)(u >> 16);
}

__device__ inline int quarter_of(int c) {
    return (c >= 2 * QW) ? ((c >= 3 * QW) ? 3 : 2) : ((c >= QW) ? 1 : 0);
}

// ---------- prep: cast_x + cast_w(hi/lo) + hist4 in one launch ----------
// blocks [0,6250): cast x (1.6M float4); [6250,6570): cast W (81920);
// [6570,9695): hist over 800k edges into 4N bins.
__global__ void prep_kernel(const float* __restrict__ x, unsigned short* __restrict__ x_hi,
                            const float* __restrict__ W0, const float* __restrict__ W1,
                            const float* __restrict__ W2,
                            unsigned short* __restrict__ h0, unsigned short* __restrict__ l0,
                            unsigned short* __restrict__ h1, unsigned short* __restrict__ l1,
                            unsigned short* __restrict__ h2, unsigned short* __restrict__ l2,
                            const int* __restrict__ row, const int* __restrict__ col,
                            int* __restrict__ cnt, int n4, int E) {
    int b = blockIdx.x;
    int tid = threadIdx.x;
    if (b < 6250) {
        int i = b * 256 + tid;
        if (i < n4) {
            float4 v = reinterpret_cast<const float4*>(x)[i];
            ushort4 o;
            o.x = rne_bf16(v.x); o.y = rne_bf16(v.y); o.z = rne_bf16(v.z); o.w = rne_bf16(v.w);
            reinterpret_cast<ushort4*>(x_hi)[i] = o;
        }
    } else if (b < 6570) {
        int i = (b - 6250) * 256 + tid;
        const float* w; unsigned short *hi, *lo; int idx;
        if (i < 32768)      { w = W0; hi = h0; lo = l0; idx = i; }
        else if (i < 65536) { w = W1; hi = h1; lo = l1; idx = i - 32768; }
        else if (i < 81920) { w = W2; hi = h2; lo = l2; idx = i - 65536; }
        else return;
        float f = w[idx];
        unsigned short h = rne_bf16(f);
        float fh = __uint_as_float(((unsigned int)h) << 16);
        hi[idx] = h;
        lo[idx] = rne_bf16(f - fh);
    } else {
        int e = (b - 6570) * 256 + tid;
        if (e < E) {
            int key = row[e] * NQ + quarter_of(col[e]);
            atomicAdd(&cnt[key], 1);
        }
    }
}

// ---------- scans over 4N bins ----------
__global__ void scan1_kernel(const int* __restrict__ cnt, int* __restrict__ rowptr,
                             int* __restrict__ bsum, int NB) {
    __shared__ int s[256];
    int tid = threadIdx.x;
    int gid = blockIdx.x * 256 + tid;
    int v = (gid < NB) ? cnt[gid] : 0;
    s[tid] = v;
    __syncthreads();
    for (int off = 1; off < 256; off <<= 1) {
        int t = (tid >= off) ? s[tid - off] : 0;
        __syncthreads();
        s[tid] += t;
        __syncthreads();
    }
    if (gid < NB) rowptr[gid] = s[tid] - v;
    if (tid == 255) bsum[blockIdx.x] = s[255];
}

__global__ void scan2_kernel(int* __restrict__ bsum, int* __restrict__ boff, int nb) {
    __shared__ int s[1024];
    int tid = threadIdx.x;
    int v = (tid < nb) ? bsum[tid] : 0;
    s[tid] = v;
    __syncthreads();
    for (int off = 1; off < 1024; off <<= 1) {
        int t = (tid >= off) ? s[tid - off] : 0;
        __syncthreads();
        s[tid] += t;
        __syncthreads();
    }
    if (tid < nb) boff[tid] = s[tid] - v;
}

__global__ void scan3_kernel(int* __restrict__ rowptr, const int* __restrict__ boff,
                             int* __restrict__ cursor, int NB, int E) {
    int gid = blockIdx.x * 256 + threadIdx.x;
    if (gid < NB) {
        int v = rowptr[gid] + boff[gid >> 8];
        rowptr[gid] = v;
        cursor[gid] = v;
    } else if (gid == NB) {
        rowptr[NB] = E;
    }
}

// ---------- scatter: 8 dst ranges (XCD-affine), quarter-keyed ----------
__global__ void scatter_ranged(const int* __restrict__ row, const int* __restrict__ col,
                               const float* __restrict__ ew, int* __restrict__ cursor,
                               int2* __restrict__ ep, int E) {
    int b = blockIdx.x;
    int r = b & 7;
    int q = b >> 3;
    int nchunk = gridDim.x >> 3;
    int chunk = (E + nchunk - 1) / nchunk;
    int e0 = q * chunk;
    int e1 = e0 + chunk; if (e1 > E) e1 = E;
    int lo = r * 6250, hi = lo + 6250;
    for (int e = e0 + (int)threadIdx.x; e < e1; e += (int)blockDim.x) {
        int rw = row[e];
        if (rw >= lo && rw < hi) {
            int c = col[e];
            int key = rw * NQ + quarter_of(c);
            int p = atomicAdd(&cursor[key], 1);
            ep[p] = make_int2(c, __float_as_int(ew[e]));
        }
    }
}

// ---------- gather aggregation (bf16 src/dst), unroll x8 ----------
// edges for node n: rowptr4[4n] .. rowptr4[4n+4] (quarter-ordered cols).
__device__ inline void accum8(float* acc, uint4 a, float w) {
    acc[0] += __uint_as_float(a.x << 16) * w;
    acc[1] += __uint_as_float(a.x & 0xffff0000u) * w;
    acc[2] += __uint_as_float(a.y << 16) * w;
    acc[3] += __uint_as_float(a.y & 0xffff0000u) * w;
    acc[4] += __uint_as_float(a.z << 16) * w;
    acc[5] += __uint_as_float(a.z & 0xffff0000u) * w;
    acc[6] += __uint_as_float(a.w << 16) * w;
    acc[7] += __uint_as_float(a.w & 0xffff0000u) * w;
}

__global__ void gather_agg_bf(const unsigned short* __restrict__ src, const int* __restrict__ rowptr4,
                              const int2* __restrict__ ep, unsigned short* __restrict__ agg, int N) {
    long long t = (long long)blockIdx.x * blockDim.x + threadIdx.x;
    int wid = (int)(t >> 6);
    int lane = threadIdx.x & 63;
    int slot = lane >> 4;
    int fl = lane & 15;
    int n = wid * 4 + slot;
    if (n >= N) return;
    int beg = rowptr4[n * 4], end = rowptr4[n * 4 + 4];
    float acc[8];
#pragma unroll
    for (int j = 0; j < 8; j++) acc[j] = 0.f;
    float ds = 0.f;
    int e = beg;
    for (; e + 7 < end; e += 8) {
        int2 p[8];
#pragma unroll
        for (int u = 0; u < 8; u++) p[u] = ep[e + u];
        uint4 a[8];
#pragma unroll
        for (int u = 0; u < 8; u++)
            a[u] = *reinterpret_cast<const uint4*>(src + (size_t)p[u].x * D + fl * 8);
#pragma unroll
        for (int u = 0; u < 8; u++) {
            float w = __int_as_float(p[u].y);
            accum8(acc, a[u], w);
            ds += w;
        }
    }
    for (; e + 3 < end; e += 4) {
        int2 p[4];
#pragma unroll
        for (int u = 0; u < 4; u++) p[u] = ep[e + u];
#pragma unroll
        for (int u = 0; u < 4; u++) {
            uint4 a = *reinterpret_cast<const uint4*>(src + (size_t)p[u].x * D + fl * 8);
            float w = __int_as_float(p[u].y);
            accum8(acc, a, w);
            ds += w;
        }
    }
    for (; e < end; ++e) {
        int2 p = ep[e];
        uint4 a = *reinterpret_cast<const uint4*>(src + (size_t)p.x * D + fl * 8);
        float w = __int_as_float(p.y);
        accum8(acc, a, w);
        ds += w;
    }
    float inv = 1.0f / (ds > 1.f ? ds : 1.f);
    uint4 o;
    o.x = (unsigned int)rne_bf16(acc[0] * inv) | ((unsigned int)rne_bf16(acc[1] * inv) << 16);
    o.y = (unsigned int)rne_bf16(acc[2] * inv) | ((unsigned int)rne_bf16(acc[3] * inv) << 16);
    o.z = (unsigned int)rne_bf16(acc[4] * inv) | ((unsigned int)rne_bf16(acc[5] * inv) << 16);
    o.w = (unsigned int)rne_bf16(acc[6] * inv) | ((unsigned int)rne_bf16(acc[7] * inv) << 16);
    *reinterpret_cast<uint4*>(agg + (size_t)n * D + fl * 8) = o;
}

// ---------- MFMA GEMM, whole-K W slice in LDS, one barrier (R9) ----------
template<bool RELU, bool BF16OUT, int OSTRIDE>
__global__ __launch_bounds__(256) void sage_gemm(
    const unsigned short* __restrict__ src, const unsigned short* __restrict__ agg,
    const unsigned short* __restrict__ Whi, const unsigned short* __restrict__ Wlo,
    const float* __restrict__ bias, float* __restrict__ outf,
    unsigned short* __restrict__ outb, int N) {
    __shared__ short sW[2][32][260];
    int tid = threadIdx.x;
    int c0 = blockIdx.y * 32;

    for (int i = tid; i < 2048; i += 256) {
        int h = i >> 10;
        int rem = i & 1023;
        int r = rem & 31;
        int k8 = rem >> 5;
        const unsigned short* wp = (h ? Wlo : Whi) + (size_t)(c0 + r) * K2 + k8 * 8;
        *reinterpret_cast<uint4*>(&sW[h][r][k8 * 8]) = *reinterpret_cast<const uint4*>(wp);
    }
    __syncthreads();

    int lane = tid & 63;
    int wv = tid >> 6;
    int nlane = lane & 15;
    int quad = lane >> 4;
    int m0 = blockIdx.x * 128 + wv * 32;
    int r0 = m0 + nlane;      if (r0 >= N) r0 = N - 1;   // clamped; stores guarded
    int r1 = m0 + 16 + nlane; if (r1 >= N) r1 = N - 1;

    short8 a[2][8];
#pragma unroll
    for (int ks = 0; ks < 8; ks++) {
        int k0 = ks * 32;
        const unsigned short* p0 = (k0 < D) ? (src + (size_t)r0 * D + k0)
                                            : (agg + (size_t)r0 * D + (k0 - D));
        const unsigned short* p1 = (k0 < D) ? (src + (size_t)r1 * D + k0)
                                            : (agg + (size_t)r1 * D + (k0 - D));
        a[0][ks] = *reinterpret_cast<const short8*>(p0 + quad * 8);
        a[1][ks] = *reinterpret_cast<const short8*>(p1 + quad * 8);
    }

    floatx4 acc[2][2];
#pragma unroll
    for (int mt = 0; mt < 2; mt++)
#pragma unroll
        for (int nt = 0; nt < 2; nt++) acc[mt][nt] = (floatx4){0.f, 0.f, 0.f, 0.f};

#pragma unroll
    for (int ks = 0; ks < 8; ks++) {
        int k0 = ks * 32;
#pragma unroll
        for (int nt = 0; nt < 2; nt++) {
            short8 bh = *reinterpret_cast<const short8*>(&sW[0][nt * 16 + nlane][k0 + quad * 8]);
            short8 bl = *reinterpret_cast<const short8*>(&sW[1][nt * 16 + nlane][k0 + quad * 8]);
            acc[0][nt] = __builtin_amdgcn_mfma_f32_16x16x32_bf16(a[0][ks], bh, acc[0][nt], 0, 0, 0);
            acc[0][nt] = __builtin_amdgcn_mfma_f32_16x16x32_bf16(a[0][ks], bl, acc[0][nt], 0, 0, 0);
            acc[1][nt] = __builtin_amdgcn_mfma_f32_16x16x32_bf16(a[1][ks], bh, acc[1][nt], 0, 0, 0);
            acc[1][nt] = __builtin_amdgcn_mfma_f32_16x16x32_bf16(a[1][ks], bl, acc[1][nt], 0, 0, 0);
        }
    }

#pragma unroll
    for (int nt = 0; nt < 2; nt++) {
        int c = c0 + nt * 16 + nlane;
        float bb = bias[c];
#pragma unroll
        for (int mt = 0; mt < 2; mt++) {
#pragma unroll
            for (int r = 0; r < 4; r++) {
                int node = m0 + mt * 16 + quad * 4 + r;
                if (node < N) {
                    float y = acc[mt][nt][r] + bb;
                    if (RELU) y = y > 0.f ? y : 0.f;
                    if (BF16OUT) outb[(size_t)node * OSTRIDE + c] = rne_bf16(y);
                    else         outf[(size_t)node * OSTRIDE + c] = y;
                }
            }
        }
    }
}

extern "C" void kernel_launch(void* const* d_in, const int* in_sizes, int n_in,
                              void* d_out, int out_size, void* d_ws, size_t ws_size,
                              hipStream_t stream) {
    const float* x  = (const float*)d_in[0];
    const int*   ei = (const int*)d_in[1];
    const float* ew = (const float*)d_in[2];
    const float* W0 = (const float*)d_in[3];
    const float* b0 = (const float*)d_in[4];
    const float* W1 = (const float*)d_in[5];
    const float* b1 = (const float*)d_in[6];
    const float* W2 = (const float*)d_in[7];
    const float* b2 = (const float*)d_in[8];
    float* out = (float*)d_out;

    const int N = 50000;
    const int E = in_sizes[2];          // 800000
    const int NB = N * NQ;              // 200000 bins
    const int* row = ei;
    const int* col = ei + E;

    char* base = (char*)d_ws;
    size_t ND = (size_t)N * D;
    unsigned short* x_hi   = (unsigned short*)base;               base += ND * 2;
    unsigned short* h0_hi  = (unsigned short*)base;               base += ND * 2;
    unsigned short* h1_hi  = (unsigned short*)base;               base += ND * 2;
    unsigned short* agg_hi = (unsigned short*)base;               base += ND * 2;
    int2* ep               = (int2*)base;                         base += (size_t)E * 8;
    int* rowptr4           = (int*)base;                          base += (size_t)(NB + 1) * 4;
    unsigned short* W0hi   = (unsigned short*)base;               base += 128 * 256 * 2;
    unsigned short* W0lo   = (unsigned short*)base;               base += 128 * 256 * 2;
    unsigned short* W1hi   = (unsigned short*)base;               base += 128 * 256 * 2;
    unsigned short* W1lo   = (unsigned short*)base;               base += 128 * 256 * 2;
    unsigned short* W2hi   = (unsigned short*)base;               base += 64 * 256 * 2;
    unsigned short* W2lo   = (unsigned short*)base;               base += 64 * 256 * 2;

    // CSR scratch aliases h0_hi (12.8MB; dead until layer-0 GEMM writes it)
    int* cnt    = (int*)h0_hi;          // NB ints
    int* cursor = cnt + NB;             // NB ints
    int* bsum   = cursor + NB;          // <=1024
    int* boff   = bsum + 1024;          // <=1024

    int nbScan = (NB + 255) / 256;      // 782

    // ---- prep (cast x, cast W hi/lo, hist4) ----
    hipMemsetAsync(cnt, 0, (size_t)NB * sizeof(int), stream);
    int n4 = (int)(ND / 4);             // 1,600,000
    prep_kernel<<<9695, 256, 0, stream>>>(x, x_hi, W0, W1, W2,
        W0hi, W0lo, W1hi, W1lo, W2hi, W2lo, row, col, cnt, n4, E);

    // ---- scans + scatter ----
    scan1_kernel<<<nbScan, 256, 0, stream>>>(cnt, rowptr4, bsum, NB);
    scan2_kernel<<<1, 1024, 0, stream>>>(bsum, boff, nbScan);
    scan3_kernel<<<(NB + 256) / 256 + 1, 256, 0, stream>>>(rowptr4, boff, cursor, NB, E);
    scatter_ranged<<<2048, 256, 0, stream>>>(row, col, ew, cursor, ep, E);

    int nWaves = (N + 3) / 4;                       // 12500 (4 nodes/wave)
    int aggBlocks = (int)(((long long)nWaves * 64 + 255) / 256);
    int nodeTiles = (N + 127) / 128;                // 391
    dim3 g128(nodeTiles, 4);                        // OUT=128: four 32-col tiles
    dim3 g64(nodeTiles, 2);                         // OUT=64:  two 32-col tiles

    // layer 0: x -> h0
    gather_agg_bf<<<aggBlocks, 256, 0, stream>>>(x_hi, rowptr4, ep, agg_hi, N);
    sage_gemm<true, true, D><<<g128, 256, 0, stream>>>(
        x_hi, agg_hi, W0hi, W0lo, b0, nullptr, h0_hi, N);

    // layer 1: h0 -> h1
    gather_agg_bf<<<aggBlocks, 256, 0, stream>>>(h0_hi, rowptr4, ep, agg_hi, N);
    sage_gemm<true, true, D><<<g128, 256, 0, stream>>>(
        h0_hi, agg_hi, W1hi, W1lo, b1, nullptr, h1_hi, N);

    // layer 2: h1 -> out (OUT=64, no relu, fp32)
    gather_agg_bf<<<aggBlocks, 256, 0, stream>>>(h1_hi, rowptr4, ep, agg_hi, N);
    sage_gemm<false, false, 64><<<g64, 256, 0, stream>>>(
        h1_hi, agg_hi, W2hi, W2lo, b2, out, nullptr, N);
}

// Round 12
// 322.436 us; speedup vs baseline: 1.1676x; 1.0338x over previous
//
#include <hip/hip_runtime.h>

// GraphSAGE 3-layer, N=50000, E=800000, D=128, D_OUT=64.
// R12: layer-2 transform-before-aggregate: z2 = h1@W2_bot^T (bf16, 64-wide)
// and ytop2 = h1@W2_top^T + b2 (fp32) in one K=128 MFMA GEMM; gather then
// reads 128B z2 rows (half of h1's 256B) and writes out directly.
// Layers 0/1 and CSR build unchanged from R11.

#define D 128
#define K2 256
#define NQ 4            // col quarters
#define QW 12500        // quarter width (N/4)

typedef __attribute__((ext_vector_type(8))) short short8;
typedef __attribute__((ext_vector_type(4))) float floatx4;

__device__ inline unsigned short rne_bf16(float f) {
    unsigned int u = __float_as_uint(f);
    u += 0x7fffu + ((u >> 16) & 1u);
    return (unsigned short)(u >> 16);
}

__device__ inline int quarter_of(int c) {
    return (c >= 2 * QW) ? ((c >= 3 * QW) ? 3 : 2) : ((c >= QW) ? 1 : 0);
}

// ---------- prep: cast_x + cast_w(hi/lo) + hist4 in one launch ----------
// W2 is packed into concatenated layout Wcat[r][k], r<64: W2[r][k] (top half),
// r>=64: W2[r-64][128+k] (bottom half). 128x128.
__global__ void prep_kernel(const float* __restrict__ x, unsigned short* __restrict__ x_hi,
                            const float* __restrict__ W0, const float* __restrict__ W1,
                            const float* __restrict__ W2,
                            unsigned short* __restrict__ h0, unsigned short* __restrict__ l0,
                            unsigned short* __restrict__ h1, unsigned short* __restrict__ l1,
                            unsigned short* __restrict__ h2, unsigned short* __restrict__ l2,
                            const int* __restrict__ row, const int* __restrict__ col,
                            int* __restrict__ cnt, int n4, int E) {
    int b = blockIdx.x;
    int tid = threadIdx.x;
    if (b < 6250) {
        int i = b * 256 + tid;
        if (i < n4) {
            float4 v = reinterpret_cast<const float4*>(x)[i];
            ushort4 o;
            o.x = rne_bf16(v.x); o.y = rne_bf16(v.y); o.z = rne_bf16(v.z); o.w = rne_bf16(v.w);
            reinterpret_cast<ushort4*>(x_hi)[i] = o;
        }
    } else if (b < 6570) {
        int i = (b - 6250) * 256 + tid;
        const float* w; unsigned short *hi, *lo; int sidx, didx;
        if (i < 32768)      { w = W0; hi = h0; lo = l0; sidx = i; didx = i; }
        else if (i < 65536) { w = W1; hi = h1; lo = l1; sidx = i - 32768; didx = sidx; }
        else if (i < 81920) {
            w = W2; hi = h2; lo = l2;
            int i2 = i - 65536;            // 0..16383 over Wcat 128x128
            int r = i2 >> 7, k = i2 & 127;
            sidx = (r < 64) ? (r * 256 + k) : ((r - 64) * 256 + 128 + k);
            didx = i2;
        }
        else return;
        float f = w[sidx];
        unsigned short h = rne_bf16(f);
        float fh = __uint_as_float(((unsigned int)h) << 16);
        hi[didx] = h;
        lo[didx] = rne_bf16(f - fh);
    } else {
        int e = (b - 6570) * 256 + tid;
        if (e < E) {
            int key = row[e] * NQ + quarter_of(col[e]);
            atomicAdd(&cnt[key], 1);
        }
    }
}

// ---------- scans over 4N bins ----------
__global__ void scan1_kernel(const int* __restrict__ cnt, int* __restrict__ rowptr,
                             int* __restrict__ bsum, int NB) {
    __shared__ int s[256];
    int tid = threadIdx.x;
    int gid = blockIdx.x * 256 + tid;
    int v = (gid < NB) ? cnt[gid] : 0;
    s[tid] = v;
    __syncthreads();
    for (int off = 1; off < 256; off <<= 1) {
        int t = (tid >= off) ? s[tid - off] : 0;
        __syncthreads();
        s[tid] += t;
        __syncthreads();
    }
    if (gid < NB) rowptr[gid] = s[tid] - v;
    if (tid == 255) bsum[blockIdx.x] = s[255];
}

__global__ void scan2_kernel(int* __restrict__ bsum, int* __restrict__ boff, int nb) {
    __shared__ int s[1024];
    int tid = threadIdx.x;
    int v = (tid < nb) ? bsum[tid] : 0;
    s[tid] = v;
    __syncthreads();
    for (int off = 1; off < 1024; off <<= 1) {
        int t = (tid >= off) ? s[tid - off] : 0;
        __syncthreads();
        s[tid] += t;
        __syncthreads();
    }
    if (tid < nb) boff[tid] = s[tid] - v;
}

__global__ void scan3_kernel(int* __restrict__ rowptr, const int* __restrict__ boff,
                             int* __restrict__ cursor, int NB, int E) {
    int gid = blockIdx.x * 256 + threadIdx.x;
    if (gid < NB) {
        int v = rowptr[gid] + boff[gid >> 8];
        rowptr[gid] = v;
        cursor[gid] = v;
    } else if (gid == NB) {
        rowptr[NB] = E;
    }
}

// ---------- scatter: 8 dst ranges (XCD-affine), quarter-keyed ----------
__global__ void scatter_ranged(const int* __restrict__ row, const int* __restrict__ col,
                               const float* __restrict__ ew, int* __restrict__ cursor,
                               int2* __restrict__ ep, int E) {
    int b = blockIdx.x;
    int r = b & 7;
    int q = b >> 3;
    int nchunk = gridDim.x >> 3;
    int chunk = (E + nchunk - 1) / nchunk;
    int e0 = q * chunk;
    int e1 = e0 + chunk; if (e1 > E) e1 = E;
    int lo = r * 6250, hi = lo + 6250;
    for (int e = e0 + (int)threadIdx.x; e < e1; e += (int)blockDim.x) {
        int rw = row[e];
        if (rw >= lo && rw < hi) {
            int c = col[e];
            int key = rw * NQ + quarter_of(c);
            int p = atomicAdd(&cursor[key], 1);
            ep[p] = make_int2(c, __float_as_int(ew[e]));
        }
    }
}

// ---------- gather aggregation (bf16 src/dst), unroll x8 (layers 0/1) ----------
__device__ inline void accum8(float* acc, uint4 a, float w) {
    acc[0] += __uint_as_float(a.x << 16) * w;
    acc[1] += __uint_as_float(a.x & 0xffff0000u) * w;
    acc[2] += __uint_as_float(a.y << 16) * w;
    acc[3] += __uint_as_float(a.y & 0xffff0000u) * w;
    acc[4] += __uint_as_float(a.z << 16) * w;
    acc[5] += __uint_as_float(a.z & 0xffff0000u) * w;
    acc[6] += __uint_as_float(a.w << 16) * w;
    acc[7] += __uint_as_float(a.w & 0xffff0000u) * w;
}

__global__ void gather_agg_bf(const unsigned short* __restrict__ src, const int* __restrict__ rowptr4,
                              const int2* __restrict__ ep, unsigned short* __restrict__ agg, int N) {
    long long t = (long long)blockIdx.x * blockDim.x + threadIdx.x;
    int wid = (int)(t >> 6);
    int lane = threadIdx.x & 63;
    int slot = lane >> 4;
    int fl = lane & 15;
    int n = wid * 4 + slot;
    if (n >= N) return;
    int beg = rowptr4[n * 4], end = rowptr4[n * 4 + 4];
    float acc[8];
#pragma unroll
    for (int j = 0; j < 8; j++) acc[j] = 0.f;
    float ds = 0.f;
    int e = beg;
    for (; e + 7 < end; e += 8) {
        int2 p[8];
#pragma unroll
        for (int u = 0; u < 8; u++) p[u] = ep[e + u];
        uint4 a[8];
#pragma unroll
        for (int u = 0; u < 8; u++)
            a[u] = *reinterpret_cast<const uint4*>(src + (size_t)p[u].x * D + fl * 8);
#pragma unroll
        for (int u = 0; u < 8; u++) {
            float w = __int_as_float(p[u].y);
            accum8(acc, a[u], w);
            ds += w;
        }
    }
    for (; e + 3 < end; e += 4) {
        int2 p[4];
#pragma unroll
        for (int u = 0; u < 4; u++) p[u] = ep[e + u];
#pragma unroll
        for (int u = 0; u < 4; u++) {
            uint4 a = *reinterpret_cast<const uint4*>(src + (size_t)p[u].x * D + fl * 8);
            float w = __int_as_float(p[u].y);
            accum8(acc, a, w);
            ds += w;
        }
    }
    for (; e < end; ++e) {
        int2 p = ep[e];
        uint4 a = *reinterpret_cast<const uint4*>(src + (size_t)p.x * D + fl * 8);
        float w = __int_as_float(p.y);
        accum8(acc, a, w);
        ds += w;
    }
    float inv = 1.0f / (ds > 1.f ? ds : 1.f);
    uint4 o;
    o.x = (unsigned int)rne_bf16(acc[0] * inv) | ((unsigned int)rne_bf16(acc[1] * inv) << 16);
    o.y = (unsigned int)rne_bf16(acc[2] * inv) | ((unsigned int)rne_bf16(acc[3] * inv) << 16);
    o.z = (unsigned int)rne_bf16(acc[4] * inv) | ((unsigned int)rne_bf16(acc[5] * inv) << 16);
    o.w = (unsigned int)rne_bf16(acc[6] * inv) | ((unsigned int)rne_bf16(acc[7] * inv) << 16);
    *reinterpret_cast<uint4*>(agg + (size_t)n * D + fl * 8) = o;
}

// ---------- MFMA GEMM, whole-K W slice in LDS, one barrier (layers 0/1) ----------
template<bool RELU, bool BF16OUT, int OSTRIDE>
__global__ __launch_bounds__(256) void sage_gemm(
    const unsigned short* __restrict__ src, const unsigned short* __restrict__ agg,
    const unsigned short* __restrict__ Whi, const unsigned short* __restrict__ Wlo,
    const float* __restrict__ bias, float* __restrict__ outf,
    unsigned short* __restrict__ outb, int N) {
    __shared__ short sW[2][32][260];
    int tid = threadIdx.x;
    int c0 = blockIdx.y * 32;

    for (int i = tid; i < 2048; i += 256) {
        int h = i >> 10;
        int rem = i & 1023;
        int r = rem & 31;
        int k8 = rem >> 5;
        const unsigned short* wp = (h ? Wlo : Whi) + (size_t)(c0 + r) * K2 + k8 * 8;
        *reinterpret_cast<uint4*>(&sW[h][r][k8 * 8]) = *reinterpret_cast<const uint4*>(wp);
    }
    __syncthreads();

    int lane = tid & 63;
    int wv = tid >> 6;
    int nlane = lane & 15;
    int quad = lane >> 4;
    int m0 = blockIdx.x * 128 + wv * 32;
    int r0 = m0 + nlane;      if (r0 >= N) r0 = N - 1;   // clamped; stores guarded
    int r1 = m0 + 16 + nlane; if (r1 >= N) r1 = N - 1;

    short8 a[2][8];
#pragma unroll
    for (int ks = 0; ks < 8; ks++) {
        int k0 = ks * 32;
        const unsigned short* p0 = (k0 < D) ? (src + (size_t)r0 * D + k0)
                                            : (agg + (size_t)r0 * D + (k0 - D));
        const unsigned short* p1 = (k0 < D) ? (src + (size_t)r1 * D + k0)
                                            : (agg + (size_t)r1 * D + (k0 - D));
        a[0][ks] = *reinterpret_cast<const short8*>(p0 + quad * 8);
        a[1][ks] = *reinterpret_cast<const short8*>(p1 + quad * 8);
    }

    floatx4 acc[2][2];
#pragma unroll
    for (int mt = 0; mt < 2; mt++)
#pragma unroll
        for (int nt = 0; nt < 2; nt++) acc[mt][nt] = (floatx4){0.f, 0.f, 0.f, 0.f};

#pragma unroll
    for (int ks = 0; ks < 8; ks++) {
        int k0 = ks * 32;
#pragma unroll
        for (int nt = 0; nt < 2; nt++) {
            short8 bh = *reinterpret_cast<const short8*>(&sW[0][nt * 16 + nlane][k0 + quad * 8]);
            short8 bl = *reinterpret_cast<const short8*>(&sW[1][nt * 16 + nlane][k0 + quad * 8]);
            acc[0][nt] = __builtin_amdgcn_mfma_f32_16x16x32_bf16(a[0][ks], bh, acc[0][nt], 0, 0, 0);
            acc[0][nt] = __builtin_amdgcn_mfma_f32_16x16x32_bf16(a[0][ks], bl, acc[0][nt], 0, 0, 0);
            acc[1][nt] = __builtin_amdgcn_mfma_f32_16x16x32_bf16(a[1][ks], bh, acc[1][nt], 0, 0, 0);
            acc[1][nt] = __builtin_amdgcn_mfma_f32_16x16x32_bf16(a[1][ks], bl, acc[1][nt], 0, 0, 0);
        }
    }

#pragma unroll
    for (int nt = 0; nt < 2; nt++) {
        int c = c0 + nt * 16 + nlane;
        float bb = bias[c];
#pragma unroll
        for (int mt = 0; mt < 2; mt++) {
#pragma unroll
            for (int r = 0; r < 4; r++) {
                int node = m0 + mt * 16 + quad * 4 + r;
                if (node < N) {
                    float y = acc[mt][nt][r] + bb;
                    if (RELU) y = y > 0.f ? y : 0.f;
                    if (BF16OUT) outb[(size_t)node * OSTRIDE + c] = rne_bf16(y);
                    else         outf[(size_t)node * OSTRIDE + c] = y;
                }
            }
        }
    }
}

// ---------- layer-2 GEMM (K=128): ytop2 = h1@Wtop^T + b2 (fp32), z2 = h1@Wbot^T (bf16)
// Wcat 128x128 (rows 0..63 = W2 top-half-K, 64..127 = W2 bottom-half-K).
__global__ __launch_bounds__(256) void sage_gemm2(
    const unsigned short* __restrict__ h1, const unsigned short* __restrict__ Whi,
    const unsigned short* __restrict__ Wlo, const float* __restrict__ b2,
    float* __restrict__ ytop2, unsigned short* __restrict__ z2, int N) {
    __shared__ short sW[2][32][132];    // stride 132 shorts = 66 words = 2 mod 32
    int tid = threadIdx.x;
    int c0 = blockIdx.y * 32;

    // stage 2 x 32 rows x 16 uint4
    for (int i = tid; i < 1024; i += 256) {
        int h = i >> 9;
        int rem = i & 511;
        int r = rem & 31;
        int k8 = rem >> 5;
        const unsigned short* wp = (h ? Wlo : Whi) + (size_t)(c0 + r) * 128 + k8 * 8;
        *reinterpret_cast<uint4*>(&sW[h][r][k8 * 8]) = *reinterpret_cast<const uint4*>(wp);
    }
    __syncthreads();

    int lane = tid & 63;
    int wv = tid >> 6;
    int nlane = lane & 15;
    int quad = lane >> 4;
    int m0 = blockIdx.x * 128 + wv * 32;
    int r0 = m0 + nlane;      if (r0 >= N) r0 = N - 1;
    int r1 = m0 + 16 + nlane; if (r1 >= N) r1 = N - 1;

    short8 a[2][4];
#pragma unroll
    for (int ks = 0; ks < 4; ks++) {
        a[0][ks] = *reinterpret_cast<const short8*>(h1 + (size_t)r0 * D + ks * 32 + quad * 8);
        a[1][ks] = *reinterpret_cast<const short8*>(h1 + (size_t)r1 * D + ks * 32 + quad * 8);
    }

    floatx4 acc[2][2];
#pragma unroll
    for (int mt = 0; mt < 2; mt++)
#pragma unroll
        for (int nt = 0; nt < 2; nt++) acc[mt][nt] = (floatx4){0.f, 0.f, 0.f, 0.f};

#pragma unroll
    for (int ks = 0; ks < 4; ks++) {
        int k0 = ks * 32;
#pragma unroll
        for (int nt = 0; nt < 2; nt++) {
            short8 bh = *reinterpret_cast<const short8*>(&sW[0][nt * 16 + nlane][k0 + quad * 8]);
            short8 bl = *reinterpret_cast<const short8*>(&sW[1][nt * 16 + nlane][k0 + quad * 8]);
            acc[0][nt] = __builtin_amdgcn_mfma_f32_16x16x32_bf16(a[0][ks], bh, acc[0][nt], 0, 0, 0);
            acc[0][nt] = __builtin_amdgcn_mfma_f32_16x16x32_bf16(a[0][ks], bl, acc[0][nt], 0, 0, 0);
            acc[1][nt] = __builtin_amdgcn_mfma_f32_16x16x32_bf16(a[1][ks], bh, acc[1][nt], 0, 0, 0);
            acc[1][nt] = __builtin_amdgcn_mfma_f32_16x16x32_bf16(a[1][ks], bl, acc[1][nt], 0, 0, 0);
        }
    }

#pragma unroll
    for (int nt = 0; nt < 2; nt++) {
        int c = c0 + nt * 16 + nlane;
#pragma unroll
        for (int mt = 0; mt < 2; mt++) {
#pragma unroll
            for (int r = 0; r < 4; r++) {
                int node = m0 + mt * 16 + quad * 4 + r;
                if (node < N) {
                    float v = acc[mt][nt][r];
                    if (c < 64) ytop2[(size_t)node * 64 + c] = v + b2[c];
                    else        z2[(size_t)node * 64 + (c - 64)] = rne_bf16(v);
                }
            }
        }
    }
}

// ---------- layer-2 gather: out[n] = ytop2[n] + (sum w*z2[col])/deg ----------
// Wave = 8 slots x 8 lanes; slot = node; lane covers 8 bf16 (16B) of 128B row.
__global__ void gather_out(const unsigned short* __restrict__ z2, const int* __restrict__ rowptr4,
                           const int2* __restrict__ ep, const float* __restrict__ ytop2,
                           float* __restrict__ out, int N) {
    long long t = (long long)blockIdx.x * blockDim.x + threadIdx.x;
    int wid = (int)(t >> 6);
    int lane = threadIdx.x & 63;
    int slot = lane >> 3;
    int fl = lane & 7;
    int n = wid * 8 + slot;
    if (n >= N) return;
    int beg = rowptr4[n * 4], end = rowptr4[n * 4 + 4];
    float acc[8];
#pragma unroll
    for (int j = 0; j < 8; j++) acc[j] = 0.f;
    float ds = 0.f;
    int e = beg;
    for (; e + 7 < end; e += 8) {
        int2 p[8];
#pragma unroll
        for (int u = 0; u < 8; u++) p[u] = ep[e + u];
        uint4 a[8];
#pragma unroll
        for (int u = 0; u < 8; u++)
            a[u] = *reinterpret_cast<const uint4*>(z2 + (size_t)p[u].x * 64 + fl * 8);
#pragma unroll
        for (int u = 0; u < 8; u++) {
            float w = __int_as_float(p[u].y);
            accum8(acc, a[u], w);
            ds += w;
        }
    }
    for (; e < end; ++e) {
        int2 p = ep[e];
        uint4 a = *reinterpret_cast<const uint4*>(z2 + (size_t)p.x * 64 + fl * 8);
        float w = __int_as_float(p.y);
        accum8(acc, a, w);
        ds += w;
    }
    float inv = 1.0f / (ds > 1.f ? ds : 1.f);
    const float* yt = ytop2 + (size_t)n * 64 + fl * 8;
    float* op = out + (size_t)n * 64 + fl * 8;
    float4 t0 = *reinterpret_cast<const float4*>(yt);
    float4 t1 = *reinterpret_cast<const float4*>(yt + 4);
    float4 o0 = make_float4(t0.x + acc[0] * inv, t0.y + acc[1] * inv,
                            t0.z + acc[2] * inv, t0.w + acc[3] * inv);
    float4 o1 = make_float4(t1.x + acc[4] * inv, t1.y + acc[5] * inv,
                            t1.z + acc[6] * inv, t1.w + acc[7] * inv);
    *reinterpret_cast<float4*>(op) = o0;
    *reinterpret_cast<float4*>(op + 4) = o1;
}

extern "C" void kernel_launch(void* const* d_in, const int* in_sizes, int n_in,
                              void* d_out, int out_size, void* d_ws, size_t ws_size,
                              hipStream_t stream) {
    const float* x  = (const float*)d_in[0];
    const int*   ei = (const int*)d_in[1];
    const float* ew = (const float*)d_in[2];
    const float* W0 = (const float*)d_in[3];
    const float* b0 = (const float*)d_in[4];
    const float* W1 = (const float*)d_in[5];
    const float* b1 = (const float*)d_in[6];
    const float* W2 = (const float*)d_in[7];
    const float* b2 = (const float*)d_in[8];
    float* out = (float*)d_out;

    const int N = 50000;
    const int E = in_sizes[2];          // 800000
    const int NB = N * NQ;              // 200000 bins
    const int* row = ei;
    const int* col = ei + E;

    char* base = (char*)d_ws;
    size_t ND = (size_t)N * D;
    unsigned short* x_hi   = (unsigned short*)base;               base += ND * 2;
    unsigned short* h0_hi  = (unsigned short*)base;               base += ND * 2;
    unsigned short* h1_hi  = (unsigned short*)base;               base += ND * 2;
    unsigned short* agg_hi = (unsigned short*)base;               base += ND * 2;
    int2* ep               = (int2*)base;                         base += (size_t)E * 8;
    int* rowptr4           = (int*)base;                          base += (size_t)(NB + 1) * 4;
    unsigned short* W0hi   = (unsigned short*)base;               base += 128 * 256 * 2;
    unsigned short* W0lo   = (unsigned short*)base;               base += 128 * 256 * 2;
    unsigned short* W1hi   = (unsigned short*)base;               base += 128 * 256 * 2;
    unsigned short* W1lo   = (unsigned short*)base;               base += 128 * 256 * 2;
    unsigned short* W2Chi  = (unsigned short*)base;               base += 128 * 128 * 2;
    unsigned short* W2Clo  = (unsigned short*)base;               base += 128 * 128 * 2;

    // CSR scratch aliases h0_hi (dead until layer-0 GEMM writes it)
    int* cnt    = (int*)h0_hi;          // NB ints
    int* cursor = cnt + NB;             // NB ints
    int* bsum   = cursor + NB;          // <=1024
    int* boff   = bsum + 1024;          // <=1024

    // layer-2 scratch: ytop2 (fp32 N*64 = 12.8MB) aliases agg_hi (free after L1
    // GEMM); z2 (bf16 N*64 = 6.4MB) aliases h0_hi (free after L1 GEMM).
    float* ytop2          = (float*)agg_hi;
    unsigned short* z2    = (unsigned short*)h0_hi;

    int nbScan = (NB + 255) / 256;      // 782

    // ---- prep (cast x, cast W hi/lo, hist4) ----
    hipMemsetAsync(cnt, 0, (size_t)NB * sizeof(int), stream);
    int n4 = (int)(ND / 4);             // 1,600,000
    prep_kernel<<<9695, 256, 0, stream>>>(x, x_hi, W0, W1, W2,
        W0hi, W0lo, W1hi, W1lo, W2Chi, W2Clo, row, col, cnt, n4, E);

    // ---- scans + scatter ----
    scan1_kernel<<<nbScan, 256, 0, stream>>>(cnt, rowptr4, bsum, NB);
    scan2_kernel<<<1, 1024, 0, stream>>>(bsum, boff, nbScan);
    scan3_kernel<<<(NB + 256) / 256 + 1, 256, 0, stream>>>(rowptr4, boff, cursor, NB, E);
    scatter_ranged<<<2048, 256, 0, stream>>>(row, col, ew, cursor, ep, E);

    int nWaves = (N + 3) / 4;                       // 12500 (4 nodes/wave)
    int aggBlocks = (int)(((long long)nWaves * 64 + 255) / 256);
    int nodeTiles = (N + 127) / 128;                // 391
    dim3 g128(nodeTiles, 4);                        // OUT=128: four 32-col tiles

    // layer 0: x -> h0
    gather_agg_bf<<<aggBlocks, 256, 0, stream>>>(x_hi, rowptr4, ep, agg_hi, N);
    sage_gemm<true, true, D><<<g128, 256, 0, stream>>>(
        x_hi, agg_hi, W0hi, W0lo, b0, nullptr, h0_hi, N);

    // layer 1: h0 -> h1
    gather_agg_bf<<<aggBlocks, 256, 0, stream>>>(h0_hi, rowptr4, ep, agg_hi, N);
    sage_gemm<true, true, D><<<g128, 256, 0, stream>>>(
        h0_hi, agg_hi, W1hi, W1lo, b1, nullptr, h1_hi, N);

    // layer 2 (z-trick): h1 -> (ytop2, z2) -> out
    sage_gemm2<<<g128, 256, 0, stream>>>(h1_hi, W2Chi, W2Clo, b2, ytop2, z2, N);
    int nWaves2 = (N + 7) / 8;                      // 6250 (8 nodes/wave)
    int outBlocks = (int)(((long long)nWaves2 * 64 + 255) / 256);
    gather_out<<<outBlocks, 256, 0, stream>>>(z2, rowptr4, ep, ytop2, out, N);
}